// Round 9
// baseline (895.955 us; speedup 1.0000x reference)
//
#include <hip/hip_runtime.h>

#define IN_F 48
#define EDGE_F 32
#define HID_F 128
#define OUT_F 64

// pack layout: e in bits [0,21), s in [21,42), d in [42,63).  Requires N,E < 2^21.

// ---------------- counting-sort-by-dst preprocessing ----------------

__global__ void k_hist(const int* __restrict__ dst, int* __restrict__ cnt, int E) {
    int e = blockIdx.x * 256 + threadIdx.x;
    if (e < E) atomicAdd(&cnt[dst[e]], 1);
}

// inclusive scan of 1024-chunk -> offsets[1+g]; chunk totals -> blksum; zeroes cnt for reuse as cursor
__global__ void k_scan1(int* __restrict__ cnt, int* __restrict__ offsets,
                        int* __restrict__ blksum, int N) {
    __shared__ int sh[1024];
    int tid = threadIdx.x;
    int g = blockIdx.x * 1024 + tid;
    sh[tid] = (g < N) ? cnt[g] : 0;
    if (g < N) cnt[g] = 0;   // cursor reset folded in
    __syncthreads();
#pragma unroll
    for (int off = 1; off < 1024; off <<= 1) {
        int t = (tid >= off) ? sh[tid - off] : 0;
        __syncthreads();
        sh[tid] += t;
        __syncthreads();
    }
    if (g < N) offsets[1 + g] = sh[tid];
    if (tid == 1023) blksum[blockIdx.x] = sh[tid];
}

__global__ void k_scan2(int* __restrict__ blksum, int nb) {
    __shared__ int sh[256];
    int tid = threadIdx.x;
    int orig = (tid < nb) ? blksum[tid] : 0;
    sh[tid] = orig;
    __syncthreads();
#pragma unroll
    for (int off = 1; off < 256; off <<= 1) {
        int t = (tid >= off) ? sh[tid - off] : 0;
        __syncthreads();
        sh[tid] += t;
        __syncthreads();
    }
    if (tid < nb) blksum[tid] = sh[tid] - orig;  // exclusive
}

__global__ void k_scan3(int* __restrict__ offsets, const int* __restrict__ blksum, int N) {
    int g = blockIdx.x * 1024 + threadIdx.x;
    if (g < N) offsets[1 + g] += blksum[blockIdx.x];
    if (g == 0) offsets[0] = 0;
}

// ---------------- fill: one 8B scattered store per edge, (d,s,e) packed ----------------
__global__ void k_fill(const int* __restrict__ dst, const int* __restrict__ src,
                       const int* __restrict__ offsets, int* __restrict__ cursor,
                       unsigned long long* __restrict__ pack, int E) {
    int e = blockIdx.x * 256 + threadIdx.x;
    if (e >= E) return;
    int d = dst[e];
    int s = src[e];
    int p = atomicAdd(&cursor[d], 1);
    int pos = offsets[d] + p;
    pack[pos] = ((unsigned long long)d << 42) | ((unsigned long long)s << 21) | (unsigned long long)e;
}

// ---------------- fused edge encoder + in-LDS segment reduction ----------------
__global__ __launch_bounds__(256) void k_edge_reduce(
    const float* __restrict__ efeat, const float* __restrict__ nfeat,
    const unsigned long long* __restrict__ pack,
    const float* __restrict__ We, const float* __restrict__ be,
    float* __restrict__ hn0sum, int E)
{
    __shared__ float lmsg[256][25];   // pad 25: stride coprime with 32 banks
    __shared__ int ld[256];
    __shared__ unsigned long long hm[4];
    __shared__ int dnb[2];            // d of global predecessor / successor
    int tid = threadIdx.x;
    int B0 = blockIdx.x * 256;
    int i = B0 + tid;
    int nvalid = min(256, E - B0);
    if (tid == 0) {
        dnb[0] = (B0 > 0) ? (int)(pack[B0 - 1] >> 42) : -9;
        dnb[1] = (B0 + 256 < E) ? (int)(pack[B0 + 256] >> 42) : -9;
    }
    int d = -3, s = 0;
    float ef[EDGE_F];
    if (i < E) {
        unsigned long long v = pack[i];
        int e = (int)(v & 0x1FFFFF);
        s = (int)((v >> 21) & 0x1FFFFF);
        d = (int)(v >> 42);
        const float4* ef4 = (const float4*)(efeat + (size_t)e * EDGE_F);
#pragma unroll
        for (int q = 0; q < EDGE_F / 4; ++q) {
            float4 t = ef4[q];
            ef[4 * q + 0] = t.x; ef[4 * q + 1] = t.y; ef[4 * q + 2] = t.z; ef[4 * q + 3] = t.w;
        }
    }
    ld[tid] = d;
    __syncthreads();

    bool head = (i < E) && (tid == 0 || d != ld[tid - 1]);
    unsigned long long m = __ballot(head);
    int wv = tid >> 6, lane = tid & 63;
    if (lane == 0) hm[wv] = m;
    __syncthreads();

#pragma unroll
    for (int c = 0; c < 2; ++c) {
        if (i < E) {
            float acc[24];
#pragma unroll
            for (int j = 0; j < 24; ++j) acc[j] = be[c * 24 + j];     // wave-uniform -> s_load
#pragma unroll
            for (int k = 0; k < EDGE_F; ++k) {
                float ek = ef[k];
#pragma unroll
                for (int j = 0; j < 24; ++j)
                    acc[j] = fmaf(ek, We[k * IN_F + c * 24 + j], acc[j]);
            }
            const float4* n4 = (const float4*)(nfeat + (size_t)s * IN_F + c * 24);
#pragma unroll
            for (int q = 0; q < 6; ++q) {
                float4 nv = n4[q];
                lmsg[tid][4 * q + 0] = fmaxf(acc[4 * q + 0], 0.0f) * nv.x;
                lmsg[tid][4 * q + 1] = fmaxf(acc[4 * q + 1], 0.0f) * nv.y;
                lmsg[tid][4 * q + 2] = fmaxf(acc[4 * q + 2], 0.0f) * nv.z;
                lmsg[tid][4 * q + 3] = fmaxf(acc[4 * q + 3], 0.0f) * nv.w;
            }
        }
        __syncthreads();

        int dprev = dnb[0], dnext = dnb[1];
        unsigned long long mym = hm[wv];
        while (mym) {
            int rel = __ffsll(mym) - 1;
            mym &= mym - 1;
            int a = wv * 64 + rel;
            // find next head strictly after a
            int b = nvalid;
            {
                unsigned long long mm = (rel < 63) ? (hm[wv] & (~0ULL << (rel + 1))) : 0ULL;
                int w2 = wv;
                while (true) {
                    if (mm) { b = w2 * 64 + __ffsll(mm) - 1; break; }
                    if (++w2 >= 4) break;
                    mm = hm[w2];
                }
            }
            int dd = ld[a];
            bool cut = (a == 0 && dd == dprev) || (b == nvalid && dd == dnext);
            if (lane < 24) {
                float sum = 0.0f;
                int t = a;
                for (; t + 2 <= b; t += 2) sum += lmsg[t][lane] + lmsg[t + 1][lane];
                if (t < b) sum += lmsg[t][lane];
                float* dp = hn0sum + (size_t)dd * IN_F + c * 24 + lane;
                if (cut) atomicAdd(dp, sum);
                else *dp = sum;
            }
        }
        __syncthreads();   // lmsg reused by next chunk
    }
}

// ---------------- hcat builder: hcat = [nfeat, hn0sum/deg] ----------------
__global__ void k_hcatb(const float* __restrict__ nfeat, const float* __restrict__ hn0sum,
                        const int* __restrict__ offsets, float* __restrict__ hcat, int N) {
    int idx = blockIdx.x * 256 + threadIdx.x;
    int total = N * 12;
    if (idx >= total) return;
    int node = idx / 12;
    int q = idx - node * 12;
    float4 nv = ((const float4*)nfeat)[idx];
    float4 hv = ((const float4*)hn0sum)[idx];
    int deg = offsets[node + 1] - offsets[node];
    float ivn = 1.0f / (float)max(deg, 1);
    float4* out4 = (float4*)(hcat + (size_t)node * 96);
    out4[q] = nv;
    float4 o;
    o.x = hv.x * ivn; o.y = hv.y * ivn; o.z = hv.z * ivn; o.w = hv.w * ivn;
    out4[12 + q] = o;
}

// ---------------- mm1p: 32-row blocks, 8 rows/wave (halves per-row weight
// re-fetch from L2: each wave streams W1s+W1n+W2n=130KB regardless of row
// count, so rows/wave doubled 4->8).  hs buffer eliminated: after both W1
// phases the x-part of xs is dead, so relu'd h1 overwrites xs[row][0..128)
// in place (rows are wave-private; no barrier anywhere in this kernel).
// LDS 24.6KB -> ~6 blocks/CU keeps occupancy ~75%.
__global__ __launch_bounds__(256) void k_mm1p(
    const float* __restrict__ hcat,
    const unsigned long long* __restrict__ pack, const int* __restrict__ offsets,
    const float* __restrict__ W1s, const float* __restrict__ W1n,
    const float* __restrict__ b1, const float* __restrict__ W2n,
    float* __restrict__ h1, float* __restrict__ y2, int N) {
    __shared__ float xs[32][192];
    int wv = threadIdx.x >> 6, lane = threadIdx.x & 63;
    int base = blockIdx.x * 32;
    int r0 = wv * 8;                       // this wave's first xs row
    // ---- gather phase (scalarized, 8-deep batches = r5/r8 form) ----
#pragma unroll
    for (int rr = 0; rr < 8; ++rr) {
        int row = base + r0 + rr;
        int r_u = __builtin_amdgcn_readfirstlane(row < N ? row : N - 1);  // wave-uniform
        xs[r0 + rr][lane] = hcat[(size_t)r_u * 96 + lane];
        if (lane < 32) xs[r0 + rr][64 + lane] = hcat[(size_t)r_u * 96 + 64 + lane];
        int s0 = offsets[r_u], s1 = offsets[r_u + 1];
        float ivn = 1.0f / (float)max(s1 - s0, 1);
        float sA = 0.0f, sB = 0.0f;
        int i = s0;
        for (; i + 8 <= s1; i += 8) {
            int iu = __builtin_amdgcn_readfirstlane(i);
            int sx[8];
#pragma unroll
            for (int u = 0; u < 8; ++u)
                sx[u] = (int)((pack[(size_t)iu + u] >> 21) & 0x1FFFFF);   // uniform -> SALU
            float av[8];
#pragma unroll
            for (int u = 0; u < 8; ++u)
                av[u] = hcat[(size_t)sx[u] * 96 + lane];                  // SGPR base gather
            sA += ((av[0] + av[1]) + (av[2] + av[3])) + ((av[4] + av[5]) + (av[6] + av[7]));
            if (lane < 32) {
                float bv[8];
#pragma unroll
                for (int u = 0; u < 8; ++u)
                    bv[u] = hcat[(size_t)sx[u] * 96 + 64 + lane];
                sB += ((bv[0] + bv[1]) + (bv[2] + bv[3])) + ((bv[4] + bv[5]) + (bv[6] + bv[7]));
            }
        }
        for (; i < s1; ++i) {
            int iu = __builtin_amdgcn_readfirstlane(i);
            int sxt = (int)((pack[iu] >> 21) & 0x1FFFFF);
            sA += hcat[(size_t)sxt * 96 + lane];
            if (lane < 32) sB += hcat[(size_t)sxt * 96 + 64 + lane];
        }
        xs[r0 + rr][96 + lane] = sA * ivn;
        if (lane < 32) xs[r0 + rr][160 + lane] = sB * ivn;
    }
    // ---- matmul phase: 8 rows, 16 accumulators ----
    int c0 = lane, c1 = lane + 64;
    float a0[8], a1[8];
    float bb0 = b1[c0], bb1 = b1[c1];
#pragma unroll
    for (int r = 0; r < 8; ++r) { a0[r] = bb0; a1[r] = bb1; }
#pragma unroll 2
    for (int k = 0; k < 96; ++k) {
        float w0 = W1s[k * 128 + c0], w1 = W1s[k * 128 + c1];
#pragma unroll
        for (int r = 0; r < 8; ++r) {
            float xv = xs[r0 + r][k];
            a0[r] = fmaf(xv, w0, a0[r]);
            a1[r] = fmaf(xv, w1, a1[r]);
        }
    }
#pragma unroll 2
    for (int k = 0; k < 96; ++k) {
        float w0 = W1n[k * 128 + c0], w1 = W1n[k * 128 + c1];
#pragma unroll
        for (int r = 0; r < 8; ++r) {
            float xv = xs[r0 + r][96 + k];
            a0[r] = fmaf(xv, w0, a0[r]);
            a1[r] = fmaf(xv, w1, a1[r]);
        }
    }
    // ---- relu, store h1, overwrite xs rows with h (wave-private, no barrier) ----
#pragma unroll
    for (int r = 0; r < 8; ++r) {
        int row = base + r0 + r;
        float v0 = fmaxf(a0[r], 0.0f);
        float v1 = fmaxf(a1[r], 0.0f);
        xs[r0 + r][c0] = v0;
        xs[r0 + r][c1] = v1;
        if (row < N) {
            h1[(size_t)row * 128 + c0] = v0;
            h1[(size_t)row * 128 + c1] = v1;
        }
    }
    // ---- projection: y2 = h1 @ W2n (128 -> 64), h read back from xs ----
    float q[8];
#pragma unroll
    for (int r = 0; r < 8; ++r) q[r] = 0.0f;
#pragma unroll 2
    for (int k = 0; k < 128; ++k) {
        float w = W2n[k * 64 + lane];
#pragma unroll
        for (int r = 0; r < 8; ++r)
            q[r] = fmaf(xs[r0 + r][k], w, q[r]);
    }
#pragma unroll
    for (int r = 0; r < 8; ++r) {
        int row = base + r0 + r;
        if (row < N) y2[(size_t)row * 64 + lane] = q[r];
    }
}

// ---------------- mm2b: 32-row blocks, 8 rows/wave (same weight-reuse move);
// out = h1@W2s + b2 + mean(y2[src]); gather means kept in registers gs[8].
__global__ __launch_bounds__(256) void k_mm2b(
    const float* __restrict__ h1, const float* __restrict__ y2,
    const unsigned long long* __restrict__ pack, const int* __restrict__ offsets,
    const float* __restrict__ W2s, const float* __restrict__ b2,
    float* __restrict__ out, int N) {
    __shared__ float xs[32][128];
    int wv = threadIdx.x >> 6, lane = threadIdx.x & 63;
    int base = blockIdx.x * 32;
    int r0 = wv * 8;
    float gs[8];
#pragma unroll
    for (int rr = 0; rr < 8; ++rr) {
        int row = base + r0 + rr;
        int r_u = __builtin_amdgcn_readfirstlane(row < N ? row : N - 1);  // wave-uniform
        xs[r0 + rr][lane]      = h1[(size_t)r_u * 128 + lane];
        xs[r0 + rr][lane + 64] = h1[(size_t)r_u * 128 + lane + 64];
        int s0 = offsets[r_u], s1 = offsets[r_u + 1];
        float ivn = 1.0f / (float)max(s1 - s0, 1);
        float sum = 0.0f;
        int i = s0;
        for (; i + 8 <= s1; i += 8) {
            int iu = __builtin_amdgcn_readfirstlane(i);
            int sx[8];
#pragma unroll
            for (int u = 0; u < 8; ++u)
                sx[u] = (int)((pack[(size_t)iu + u] >> 21) & 0x1FFFFF);   // uniform -> SALU
            float av[8];
#pragma unroll
            for (int u = 0; u < 8; ++u)
                av[u] = y2[(size_t)sx[u] * 64 + lane];                    // SGPR base gather
            sum += ((av[0] + av[1]) + (av[2] + av[3])) + ((av[4] + av[5]) + (av[6] + av[7]));
        }
        for (; i < s1; ++i) {
            int iu = __builtin_amdgcn_readfirstlane(i);
            int sxt = (int)((pack[iu] >> 21) & 0x1FFFFF);
            sum += y2[(size_t)sxt * 64 + lane];
        }
        gs[rr] = sum * ivn;
    }
    // no barrier: xs rows are wave-private
    float a[8];
    float bb = b2[lane];
#pragma unroll
    for (int r = 0; r < 8; ++r) a[r] = bb;
#pragma unroll 2
    for (int k = 0; k < 128; ++k) {
        float w = W2s[k * 64 + lane];
#pragma unroll
        for (int r = 0; r < 8; ++r)
            a[r] = fmaf(xs[r0 + r][k], w, a[r]);
    }
#pragma unroll
    for (int r = 0; r < 8; ++r) {
        int row = base + r0 + r;
        if (row < N) out[(size_t)row * 64 + lane] = a[r] + gs[r];
    }
}

extern "C" void kernel_launch(void* const* d_in, const int* in_sizes, int n_in,
                              void* d_out, int out_size, void* d_ws, size_t ws_size,
                              hipStream_t stream) {
    const float* nfeat = (const float*)d_in[0];
    const float* efeat = (const float*)d_in[1];
    const int*   src   = (const int*)d_in[2];
    const int*   dst   = (const int*)d_in[3];
    const float* We    = (const float*)d_in[4];
    const float* be    = (const float*)d_in[5];
    const float* W1s   = (const float*)d_in[6];
    const float* W1n   = (const float*)d_in[7];
    const float* b1    = (const float*)d_in[8];
    const float* W2s   = (const float*)d_in[9];
    const float* W2n   = (const float*)d_in[10];
    const float* b2    = (const float*)d_in[11];
    float* out = (float*)d_out;

    int N = in_sizes[0] / IN_F;
    int E = in_sizes[2];

    // workspace layout (4B words):
    // cursor[N] | hn0sum[48N] | offsets[N+64] | blksum[256] | pack[2E] |
    // hcat[96N] | h1[128N] | y2[64N]
    // single memset covers cursor+hn0sum (contiguous 49N)
    int*                cursor  = (int*)d_ws;
    float*              hn0sum  = (float*)(cursor + N);
    int*                offsets = (int*)(hn0sum + (size_t)48 * N);
    int*                blksum  = offsets + N + 64;
    unsigned long long* pack    = (unsigned long long*)(blksum + 256);  // N even -> 8B aligned
    float*              hcat    = (float*)(pack + E);
    float*              h1      = hcat + (size_t)96 * N;
    float*              y2      = h1 + (size_t)128 * N;

    int nb = (N + 1023) / 1024;  // 98 for N=100000 (<=256 required by k_scan2)

    (void)hipMemsetAsync(cursor, 0, (size_t)49 * N * sizeof(float), stream);
    k_hist<<<(E + 255) / 256, 256, 0, stream>>>(dst, cursor, E);
    k_scan1<<<nb, 1024, 0, stream>>>(cursor, offsets, blksum, N);   // also re-zeros cursor
    k_scan2<<<1, 256, 0, stream>>>(blksum, nb);
    k_scan3<<<nb, 1024, 0, stream>>>(offsets, blksum, N);

    k_fill<<<(E + 255) / 256, 256, 0, stream>>>(dst, src, offsets, cursor, pack, E);
    k_edge_reduce<<<(E + 255) / 256, 256, 0, stream>>>(efeat, nfeat, pack, We, be, hn0sum, E);
    k_hcatb<<<(N * 12 + 255) / 256, 256, 0, stream>>>(nfeat, hn0sum, offsets, hcat, N);
    k_mm1p<<<(N + 31) / 32, 256, 0, stream>>>(hcat, pack, offsets, W1s, W1n, b1, W2n, h1, y2, N);
    k_mm2b<<<(N + 31) / 32, 256, 0, stream>>>(h1, y2, pack, offsets, W2s, b2, out, N);
}